// Round 18
// baseline (302.264 us; speedup 1.0000x reference)
//
#include <hip/hip_runtime.h>
#include <math.h>

// Problem constants
#define B_DIM 8
#define T_DIM 4096
#define K_DIM 1024   // IN_DIM
#define H_DIM 1024   // HIDDEN
#define M_DIM (B_DIM * T_DIM)   // 32768 rows
#define BK 64

#define NX8 (M_DIM * K_DIM / 8)          // 4194304 x-chunks
#define NW8 (H_DIM * K_DIM / 8)          //  131072 per weight
#define NCVT (NX8 + 2 * NW8)             // total 8-elem chunks

typedef short bf16x8 __attribute__((ext_vector_type(8)));   // 8 bf16 = 4 VGPRs
typedef float f32x4  __attribute__((ext_vector_type(4)));

// ---------- helpers ----------
__device__ __forceinline__ unsigned short f2bf(float f) {
  unsigned int u = __builtin_bit_cast(unsigned int, f);
  u += 0x7FFFu + ((u >> 16) & 1u);   // round-to-nearest-even
  return (unsigned short)(u >> 16);
}

__device__ __forceinline__ void gload_lds16(const void* g, void* l) {
  __builtin_amdgcn_global_load_lds(
      (const __attribute__((address_space(1))) unsigned int*)g,
      (__attribute__((address_space(3))) unsigned int*)l, 16, 0, 0);
}

__device__ __forceinline__ float softplus_fast(float x) {
  float e = __expf(-fabsf(x));
  return fmaxf(x, 0.f) + __logf(1.f + e);
}

// fast tanh: 1 - 2/(e^{2x}+1). e=inf -> 1, e=0 -> -1 (correct saturation).
__device__ __forceinline__ float tanh_fast(float x) {
  float e = __expf(2.f * x);
  return 1.f - 2.f * __builtin_amdgcn_rcpf(e + 1.f);
}

// LDS-only barrier (no vmcnt drain): lets in-flight global_load_lds ride
// through the epilogue. lgkmcnt covers ds_write/ds_read ordering; rule 18
// sched_barrier pins it.
#define RAW_BAR()                                                             \
  do {                                                                        \
    asm volatile("s_waitcnt lgkmcnt(0)" ::: "memory");                        \
    __builtin_amdgcn_sched_barrier(0);                                        \
    __builtin_amdgcn_s_barrier();                                             \
  } while (0)

// ---------- fused f32 -> bf16 convert: x, Wd, Wb in ONE launch ----------
__global__ __launch_bounds__(256) void k_cvt3(const float* __restrict__ x,
                                              const float* __restrict__ Wd,
                                              const float* __restrict__ Wb,
                                              unsigned short* __restrict__ xb,
                                              unsigned short* __restrict__ wdb,
                                              unsigned short* __restrict__ wbb) {
  int i = blockIdx.x * 256 + threadIdx.x;
  if (i >= NCVT) return;
  const float* src;
  unsigned short* dst;
  int j;
  if (i < NX8)                 { src = x;  dst = xb;  j = i; }
  else if (i < NX8 + NW8)      { src = Wd; dst = wdb; j = i - NX8; }
  else                         { src = Wb; dst = wbb; j = i - NX8 - NW8; }
  float4 v0 = ((const float4*)src)[j * 2 + 0];
  float4 v1 = ((const float4*)src)[j * 2 + 1];
  bf16x8 r;
  r[0] = (short)f2bf(v0.x); r[1] = (short)f2bf(v0.y);
  r[2] = (short)f2bf(v0.z); r[3] = (short)f2bf(v0.w);
  r[4] = (short)f2bf(v1.x); r[5] = (short)f2bf(v1.y);
  r[6] = (short)f2bf(v1.z); r[7] = (short)f2bf(v1.w);
  ((bf16x8*)dst)[j] = r;
}

// ---------- megakernel (R17 + epilogue-hidden boundary drains) -------------
// Grid = 8 batches x 64 col-tiles(16 cols) = 512 blocks x 256 thr (4 waves)
// -> 2 blocks/CU (LDS 74.75 KB). R17 measured 299.3 us total.
// R18 delta: m-tile boundary restructured --
//   T15: compute; s_barrier (reads consumed); stage next-m-tile kt0+kt1;
//   epilogue with RAW_BAR (lgkm-only, loads stay in flight ~600-1000 cyc);
//   one vmcnt(0)+barrier after epilogue (drain now ~free);
//   T0 of next m-tile computes pre-staged buf0, stages nothing.
// Removes the two exposed per-m-tile boundary drains; K-loop TILEs,
// XOR swizzle, setprio(1) (R16 A/B: worth ~5% here), scan math: R17-verbatim.
__global__ __launch_bounds__(256, 2) void k_mega(
    const unsigned short* __restrict__ Xb,    // [M][K] bf16 bits
    const unsigned short* __restrict__ Wdb,   // [H][K] bf16 bits
    const unsigned short* __restrict__ Wbb,   // [H][K] bf16 bits
    const float* __restrict__ bd,
    const float* __restrict__ bb,
    const float* __restrict__ A_log,
    const float* __restrict__ h0,             // [B][H]
    float* __restrict__ out)                  // [B][T][H]
{
  __shared__ unsigned short As[2][256 * BK];   // 64 KiB
  __shared__ unsigned short Bs[2][32 * BK];    //  8 KiB
  __shared__ float totA[4][16], totB[4][16];   // chunk affine totals
  __shared__ float h_state[16];                // scan state per col

  const int tid   = threadIdx.x;
  const int wg    = blockIdx.x;
  const int batch = wg & 7;        // == XCD (round-robin dispatch)
  const int jn    = wg >> 3;       // 0..63 col-tile
  const int bn    = jn * 16;

  const int w    = tid >> 6;       // wave = chunk row-group c (0..3)
  const int lane = tid & 63;
  const int c    = w;
  const int fr   = lane & 15;      // column within 16
  const int hi   = lane >> 4;      // row quad
  const int gcol = bn + fr;

  // per-thread column scalars
  const float bdv = bd[gcol];
  const float bbv = bb[gcol];
  const float Ah  = __expf(A_log[gcol]);

  // ---- staging invariants: pre-swizzled global sources (cg = c^(row&7)) --
  const unsigned short* gA[8];
  int ldsA[8];
#pragma unroll
  for (int jj = 0; jj < 8; jj++) {
    int idx = jj * 256 + tid;      // 0..2047, row 0..255
    int row = idx >> 3;
    int cg  = (idx & 7) ^ (row & 7);
    ldsA[jj] = idx * 16;
    gA[jj] = Xb + (((size_t)(batch * T_DIM + row)) << 10) + (size_t)(cg * 8);
  }
  const unsigned short* gB;
  int ldsB;
  {
    int idx = tid;                 // 256 chunks, vrow 0..31
    int vr  = idx >> 3;
    int cg  = (idx & 7) ^ (vr & 7);
    ldsB = idx * 16;
    int h = bn + (vr & 15);
    const unsigned short* Wsrc = (vr & 16) ? Wbb : Wdb;
    gB = Wsrc + (((size_t)h) << 10) + (size_t)(cg * 8);
  }

  // ---- ds_read bases: swizzled chunk hi^(fr&7) is fragment-independent ---
  const int ch0 = hi ^ (fr & 7);
  const char* bA0 = (const char*)As + ((c * 64 + fr) * 128 + ch0 * 16);
  const char* bA1 = (const char*)As + ((c * 64 + fr) * 128 + (ch0 ^ 4) * 16);
  const char* bB0 = (const char*)Bs + (fr * 128 + ch0 * 16);
  const char* bB1 = (const char*)Bs + (fr * 128 + (ch0 ^ 4) * 16);

// tile tt = mt*16 + kt; A elem-offset = mt*256*1024 + kt*64
#define STAGE(TT, D)                                                          \
  do {                                                                        \
    int aOff = (((TT) >> 4) << 18) + (((TT) & 15) << 6);                      \
    int bOff = ((TT) & 15) << 6;                                              \
    _Pragma("unroll")                                                         \
    for (int jj = 0; jj < 8; jj++)                                            \
      gload_lds16(gA[jj] + aOff, (char*)As[D] + ldsA[jj]);                    \
    gload_lds16(gB + bOff, (char*)Bs[D] + ldsB);                              \
  } while (0)

// ds_read + MFMA on buffer D (no stage, no drain)
#define COMPUTE(D)                                                            \
  do {                                                                        \
    bf16x8 Af[8], Bf[4];                                                      \
    _Pragma("unroll")                                                         \
    for (int mm = 0; mm < 4; mm++) {                                          \
      Af[mm * 2 + 0] = *(const bf16x8*)(bA0 + (D) * 32768 + mm * 2048);       \
      Af[mm * 2 + 1] = *(const bf16x8*)(bA1 + (D) * 32768 + mm * 2048);       \
    }                                                                         \
    _Pragma("unroll")                                                         \
    for (int nn = 0; nn < 2; nn++) {                                          \
      Bf[nn * 2 + 0] = *(const bf16x8*)(bB0 + (D) * 4096 + nn * 2048);        \
      Bf[nn * 2 + 1] = *(const bf16x8*)(bB1 + (D) * 4096 + nn * 2048);        \
    }                                                                         \
    __builtin_amdgcn_s_setprio(1);                                            \
    _Pragma("unroll")                                                         \
    for (int mm = 0; mm < 4; mm++)                                            \
      _Pragma("unroll")                                                       \
      for (int nn = 0; nn < 2; nn++)                                          \
        _Pragma("unroll")                                                     \
        for (int kk = 0; kk < 2; kk++)                                        \
          acc[mm][nn] = __builtin_amdgcn_mfma_f32_16x16x32_bf16(              \
              Af[mm * 2 + kk], Bf[nn * 2 + kk], acc[mm][nn], 0, 0, 0);        \
    __builtin_amdgcn_s_setprio(0);                                            \
  } while (0)

// normal mid-m-tile tile: stage next, compute current, drain, barrier
#define TILE_N(TT, D)                                                         \
  do {                                                                        \
    STAGE((TT) + 1, (D) ^ 1);                                                 \
    COMPUTE(D);                                                               \
    asm volatile("s_waitcnt vmcnt(0)" ::: "memory");                          \
    __builtin_amdgcn_s_barrier();                                             \
  } while (0)

  // prologue: stage tiles 0,1; init scan state from h0
  STAGE(0, 0);
  STAGE(1, 1);
  if (tid < 16) h_state[tid] = h0[(batch << 10) + bn + tid];
  asm volatile("s_waitcnt vmcnt(0)" ::: "memory");
  __syncthreads();

  const f32x4 z4 = {0.f, 0.f, 0.f, 0.f};

#pragma unroll 1
  for (int mt = 0; mt < 16; mt++) {
    const int base = mt * 16;
    f32x4 acc[4][2];
#pragma unroll
    for (int m = 0; m < 4; m++) { acc[m][0] = z4; acc[m][1] = z4; }

    // kt0: buf0 pre-staged & drained (prologue or previous boundary)
    COMPUTE(0);
    __builtin_amdgcn_s_barrier();       // all waves done reading buf0

    // kt1..kt14: normal pipeline (stage kt+1, compute kt, drain, barrier)
#pragma unroll
    for (int kp = 0; kp < 7; kp++) {
      TILE_N(base + 1 + 2 * kp, 1);
      TILE_N(base + 2 + 2 * kp, 0);
    }

    // kt15 boundary: stage next m-tile's kt0 early, compute, certify reads,
    // stage kt1; both ride through the epilogue (drained after it).
    if (mt < 15) STAGE(base + 16, 0);
    COMPUTE(1);                          // kt15 from buf1
    __builtin_amdgcn_s_barrier();        // all waves' buf1 reads consumed
    if (mt < 15) STAGE(base + 17, 1);

    // ---- epilogue: nonlinearity + within-chunk prefix scan + apply -------
    // C/D layout: col = lane&15, row-in-frag = hi*4 + r  [m89-verified].
    // t within chunk = m*16 + hi*4 + r; run = 4 consecutive t per (m,hi).
    float rA[4], rB[4], wAp[4][4], wBp[4][4];
#pragma unroll
    for (int m = 0; m < 4; m++) {
      float A_ = 1.f, B_ = 0.f;
#pragma unroll
      for (int r = 0; r < 4; r++) {
        float z1  = acc[m][0][r] + bdv;
        float z2  = acc[m][1][r] + bbv;
        float dlt = softplus_fast(z1);
        float av  = __expf(-dlt * Ah);
        float bv  = dlt * z2;
        B_ = fmaf(av, B_, bv);          // compose (A_,B_) then (av,bv)
        A_ *= av;
        wAp[m][r] = A_; wBp[m][r] = B_; // inclusive within-run prefix
      }
      rA[m] = A_; rB[m] = B_;           // run total
    }
    // exclusive prefix over the 16 runs (t-order rho = m*4 + hi), snapshotted
    float cA = 1.f, cB = 0.f, eA[4], eB[4];
#pragma unroll
    for (int rho = 0; rho < 16; rho++) {
      if ((rho & 3) == hi) { eA[rho >> 2] = cA; eB[rho >> 2] = cB; }
      float sa = __shfl(rA[rho >> 2], (rho & 3) * 16 + fr, 64);
      float sb = __shfl(rB[rho >> 2], (rho & 3) * 16 + fr, 64);
      cB = fmaf(sa, cB, sb);
      cA *= sa;
    }
    // (cA,cB) = full chunk total
    if (hi == 0) { totA[c][fr] = cA; totB[c][fr] = cB; }
    RAW_BAR();                          // LDS-only: stages keep flying
    float hs = h_state[fr];             // state before this m-tile
#pragma unroll
    for (int cc = 0; cc < 3; cc++) {    // compose chunks before mine
      float t2 = fmaf(totA[cc][fr], hs, totB[cc][fr]);
      hs = (cc < c) ? t2 : hs;
    }
    RAW_BAR();                          // all reads of h_state done
    if (c == 3 && hi == 0) h_state[fr] = fmaf(cA, hs, cB);

    // apply: h_t = (excl ∘ within-run) applied to hs; write tanh(h_t)
    size_t obase = (((size_t)(batch * T_DIM + mt * 256 + c * 64 + hi * 4)) << 10)
                   + (size_t)gcol;
#pragma unroll
    for (int m = 0; m < 4; m++) {
#pragma unroll
      for (int r = 0; r < 4; r++) {
        float aT = eA[m] * wAp[m][r];
        float bT = fmaf(wAp[m][r], eB[m], wBp[m][r]);
        float h  = fmaf(aT, hs, bT);
        out[obase + ((size_t)(m * 16 + r) << 10)] = tanh_fast(h);
      }
    }

    // drain boundary stages (aged ~epilogue length -> cheap) + stores
    asm volatile("s_waitcnt vmcnt(0)" ::: "memory");
    __builtin_amdgcn_s_barrier();
  }
#undef TILE_N
#undef COMPUTE
#undef STAGE
}

// ---------- launch ----------
extern "C" void kernel_launch(void* const* d_in, const int* in_sizes, int n_in,
                              void* d_out, int out_size, void* d_ws, size_t ws_size,
                              hipStream_t stream) {
  const float* x     = (const float*)d_in[0];
  const float* h0    = (const float*)d_in[1];
  const float* Wd    = (const float*)d_in[2];
  const float* bd    = (const float*)d_in[3];
  const float* Wb    = (const float*)d_in[4];
  const float* bb    = (const float*)d_in[5];
  const float* A_log = (const float*)d_in[6];
  float* out = (float*)d_out;

  char* ws = (char*)d_ws;
  unsigned short* xb  = (unsigned short*)(ws + 0);           // 64 MiB
  unsigned short* wdb = (unsigned short*)(ws + 67108864);    //  2 MiB
  unsigned short* wbb = (unsigned short*)(ws + 69206016);    //  2 MiB

  // fused converts (one launch: x, Wd, Wb)
  k_cvt3<<<(NCVT + 255) / 256, 256, 0, stream>>>(x, Wd, Wb, xb, wdb, wbb);

  // fused dual GEMM + chunked scan + tanh; 512 blocks (2/CU), 256 thr
  k_mega<<<512, 256, 0, stream>>>(xb, wdb, wbb, bd, bb, A_log, h0, out);
}